// Round 1
// baseline (193.918 us; speedup 1.0000x reference)
//
#include <hip/hip_runtime.h>

// LSTM (B=8192, T=168, F=64, H=50) + MLP head, fused, f16 MFMA + fp32 state.
// Layout: padded gate-major cols (256 = 4 gates x 64 units), 16 rows/block,
// 4 waves/block each owning 16 units x all 4 gates -> gate math in registers.

#define B_N 8192
#define T_N 168
#define F_N 64
#define H_N 50
#define HEAD_N 100
#define ROWSTRIDE (T_N * F_N)  // 10752

typedef _Float16 f16x8 __attribute__((ext_vector_type(8)));
typedef _Float16 f16x4 __attribute__((ext_vector_type(4)));
typedef float    f32x4 __attribute__((ext_vector_type(4)));

__device__ __forceinline__ float fast_rcp(float x) { return __builtin_amdgcn_rcpf(x); }
__device__ __forceinline__ float sigm(float x) {
    float e = __expf(-x);
    return fast_rcp(1.0f + e);
}
__device__ __forceinline__ float tanh_fast(float x) {
    float a = fabsf(x);
    float e = __expf(-2.0f * a);                 // in (0,1], no overflow ever
    float t = (1.0f - e) * fast_rcp(1.0f + e);
    return copysignf(t, x);
}

__launch_bounds__(256, 2)
__global__ void lstm_fused(const float* __restrict__ x,
                           const float* __restrict__ Wx,
                           const float* __restrict__ Wh,
                           const float* __restrict__ b,
                           const float* __restrict__ W1,
                           const float* __restrict__ b1,
                           const float* __restrict__ W2,
                           const float* __restrict__ b2,
                           float* __restrict__ out)
{
    // stride 72 f16 (144 B): 16B-aligned rows, 2-way LDS bank alias only (free)
    __shared__ alignas(16) _Float16 x_lds[16][72];
    __shared__ alignas(16) _Float16 h_lds[16][72];
    __shared__ float hrelu[16][HEAD_N];

    const int tid  = threadIdx.x;
    const int lane = tid & 63;
    const int w    = tid >> 6;        // wave id 0..3 = unit-tile (16 units each)
    const int rowA = lane & 15;       // A-frag row == C-frag col
    const int kg   = lane >> 4;       // k-group 0..3
    const int R0   = blockIdx.x * 16; // batch rows of this block

    // ---------------- weight B-fragments (held in VGPRs for all 168 steps) --
    // padded col layout: col256 = g*64 + j ; this wave: j in [16w, 16w+16)
    f16x8 wxf[4][2], whf[4][2];
    float bg[4];
    const int  jl = w * 16 + rowA;    // unit index 0..63 (lane's column)
    const bool jv = (jl < H_N);
    #pragma unroll
    for (int g = 0; g < 4; ++g) {
        bg[g] = jv ? b[g * H_N + jl] : 0.0f;
        #pragma unroll
        for (int ks = 0; ks < 2; ++ks) {
            f16x8 vx, vh;
            #pragma unroll
            for (int i = 0; i < 8; ++i) {
                int k = ks * 32 + kg * 8 + i;   // same k-map used for A & B -> cancels
                float xv = 0.0f, hv = 0.0f;
                if (jv)              xv = Wx[k * 200 + g * H_N + jl];   // k < 64 always
                if (jv && k < H_N)   hv = Wh[k * 200 + g * H_N + jl];
                vx[i] = (_Float16)xv;
                vh[i] = (_Float16)hv;
            }
            wxf[g][ks] = vx;
            whf[g][ks] = vh;
        }
    }

    float c[4] = {0.f, 0.f, 0.f, 0.f};   // fp32 cell state, rows kg*4+i, unit jl

    // zero h(0); pads (cols 64..71) never read by frags (k<64)
    for (int idx = tid; idx < 16 * 72; idx += 256)
        ((_Float16*)h_lds)[idx] = (_Float16)0.0f;

    // stage x(t=0): thread -> (row tid>>4, 4 floats), coalesced 256B/row
    const int xr  = tid >> 4;
    const int xf0 = (tid & 15) * 4;
    const float* xrow = x + (size_t)(R0 + xr) * ROWSTRIDE + xf0;
    {
        f32x4 xv = *reinterpret_cast<const f32x4*>(xrow);
        f16x4 xc;
        #pragma unroll
        for (int j = 0; j < 4; ++j) xc[j] = (_Float16)xv[j];
        *reinterpret_cast<f16x4*>(&x_lds[xr][xf0]) = xc;
    }
    __syncthreads();

    // ---------------- recurrence ----------------
    for (int t = 0; t < T_N; ++t) {
        // A fragments (row = lane&15, k = ks*32 + kg*8 + i)
        f16x8 xa0 = *reinterpret_cast<const f16x8*>(&x_lds[rowA][kg * 8]);
        f16x8 xa1 = *reinterpret_cast<const f16x8*>(&x_lds[rowA][32 + kg * 8]);
        f16x8 ha0 = *reinterpret_cast<const f16x8*>(&h_lds[rowA][kg * 8]);
        f16x8 ha1 = *reinterpret_cast<const f16x8*>(&h_lds[rowA][32 + kg * 8]);

        // prefetch next x tile (latency hidden under MFMA + gates)
        int tn = (t + 1 < T_N) ? t + 1 : T_N - 1;
        f32x4 xp = *reinterpret_cast<const f32x4*>(xrow + tn * F_N);

        // z = bias + x@Wx + h@Wh  (4 independent 4-deep MFMA chains)
        f32x4 acc[4];
        #pragma unroll
        for (int g = 0; g < 4; ++g) {
            f32x4 a; a[0] = bg[g]; a[1] = bg[g]; a[2] = bg[g]; a[3] = bg[g];
            a = __builtin_amdgcn_mfma_f32_16x16x32_f16(xa0, wxf[g][0], a, 0, 0, 0);
            a = __builtin_amdgcn_mfma_f32_16x16x32_f16(xa1, wxf[g][1], a, 0, 0, 0);
            a = __builtin_amdgcn_mfma_f32_16x16x32_f16(ha0, whf[g][0], a, 0, 0, 0);
            a = __builtin_amdgcn_mfma_f32_16x16x32_f16(ha1, whf[g][1], a, 0, 0, 0);
            acc[g] = a;
        }

        // gates: all 4 gates of unit jl for rows kg*4+i are in this lane's regs
        _Float16 hn[4];
        #pragma unroll
        for (int i = 0; i < 4; ++i) {
            float zi = acc[0][i], zf = acc[1][i], zg = acc[2][i], zo = acc[3][i];
            float cn = sigm(zf) * c[i] + sigm(zi) * tanh_fast(zg);
            c[i] = cn;
            hn[i] = (_Float16)(sigm(zo) * tanh_fast(cn));   // = 0 for padded units
        }

        __syncthreads();   // all waves done reading x_lds/h_lds of step t

        #pragma unroll
        for (int i = 0; i < 4; ++i)
            h_lds[kg * 4 + i][jl] = hn[i];   // disjoint (row, unit) per thread

        {
            f16x4 xc;
            #pragma unroll
            for (int j = 0; j < 4; ++j) xc[j] = (_Float16)xp[j];
            *reinterpret_cast<f16x4*>(&x_lds[xr][xf0]) = xc;
        }
        __syncthreads();   // h(t+1), x(t+1) visible
    }

    // ---------------- MLP head: relu(h@W1 + b1)@W2 + b2 + x[:, -1, 0] -------
    {
        const int r1 = tid & 15;
        const int u1 = tid >> 4;
        float hrow[H_N];
        #pragma unroll
        for (int k = 0; k < H_N; ++k) hrow[k] = (float)h_lds[r1][k];
        for (int uu = u1; uu < HEAD_N; uu += 16) {
            float s = b1[uu];
            #pragma unroll
            for (int k = 0; k < H_N; ++k) s += hrow[k] * W1[k * HEAD_N + uu];
            hrelu[r1][uu] = fmaxf(s, 0.0f);
        }
    }
    __syncthreads();
    {
        const int r2 = tid >> 4;
        const int p  = tid & 15;
        float s = 0.0f;
        for (int uu = p; uu < HEAD_N; uu += 16) s += hrelu[r2][uu] * W2[uu];
        #pragma unroll
        for (int off = 8; off > 0; off >>= 1) s += __shfl_xor(s, off, 16);
        if (p == 0) {
            float res = x[(size_t)(R0 + r2) * ROWSTRIDE + (T_N - 1) * F_N + 0];
            out[R0 + r2] = s + b2[0] + res;
        }
    }
}

extern "C" void kernel_launch(void* const* d_in, const int* in_sizes, int n_in,
                              void* d_out, int out_size, void* d_ws, size_t ws_size,
                              hipStream_t stream) {
    const float* x  = (const float*)d_in[0];
    const float* Wx = (const float*)d_in[1];
    const float* Wh = (const float*)d_in[2];
    const float* b  = (const float*)d_in[3];
    const float* W1 = (const float*)d_in[4];
    const float* b1 = (const float*)d_in[5];
    const float* W2 = (const float*)d_in[6];
    const float* b2 = (const float*)d_in[7];
    float* out = (float*)d_out;

    lstm_fused<<<dim3(B_N / 16), dim3(256), 0, stream>>>(x, Wx, Wh, b, W1, b1, W2, b2, out);
}

// Round 2
// 184.002 us; speedup vs baseline: 1.0539x; 1.0539x over previous
//
#include <hip/hip_runtime.h>

// LSTM (B=8192, T=168, F=64, H=50) + MLP head, fused, f16 MFMA + fp32 state.
// Round 2: double-buffered LDS (1 barrier/step), cheap branchless sigm/tanh
// (exp+rcp each), 2x-unrolled step loop (compile-time buffer select),
// pointer-walk x prefetch issued early.

#define B_N 8192
#define T_N 168
#define F_N 64
#define H_N 50
#define HEAD_N 100
#define ROWSTRIDE (T_N * F_N)  // 10752

typedef _Float16 f16x8 __attribute__((ext_vector_type(8)));
typedef _Float16 f16x4 __attribute__((ext_vector_type(4)));
typedef float    f32x4 __attribute__((ext_vector_type(4)));

__device__ __forceinline__ float rcp_f(float v) { return __builtin_amdgcn_rcpf(v); }
// sigm: 2 VALU + 2 trans; exact limits 0/1 at -inf/+inf
__device__ __forceinline__ float sigm_f(float v) { return rcp_f(1.0f + __expf(-v)); }
// tanh = 1 - 2/(e^{2x}+1): 3 VALU + 2 trans; e^{2x}->inf gives exactly 1, ->0 gives -1
__device__ __forceinline__ float tanh_f(float v) {
    return fmaf(-2.0f, rcp_f(1.0f + __expf(2.0f * v)), 1.0f);
}

__launch_bounds__(256, 2)
__global__ void lstm_fused(const float* __restrict__ x,
                           const float* __restrict__ Wx,
                           const float* __restrict__ Wh,
                           const float* __restrict__ b,
                           const float* __restrict__ W1,
                           const float* __restrict__ b1,
                           const float* __restrict__ W2,
                           const float* __restrict__ b2,
                           float* __restrict__ out)
{
    // stride 72 f16 (144 B): rows 16B-aligned, worst 2-way LDS bank alias (free)
    __shared__ alignas(16) _Float16 xb[2][16][72];
    __shared__ alignas(16) _Float16 hb[2][16][72];
    __shared__ float hrelu[16][HEAD_N];

    const int tid  = threadIdx.x;
    const int lane = tid & 63;
    const int w    = tid >> 6;        // wave id = unit-tile (16 units each)
    const int rowA = lane & 15;       // A-frag row == C-frag col
    const int kg   = lane >> 4;       // k-group 0..3
    const int R0   = blockIdx.x * 16; // batch rows of this block

    // ---- weight B-fragments, resident in VGPRs for all 168 steps ----------
    // padded col layout: col256 = g*64 + j ; this wave: j in [16w, 16w+16)
    f16x8 wxf[4][2], whf[4][2];
    float bg[4];
    const int  jl = w * 16 + rowA;    // unit index 0..63 (lane's column)
    const bool jv = (jl < H_N);
    #pragma unroll
    for (int g = 0; g < 4; ++g) {
        bg[g] = jv ? b[g * H_N + jl] : 0.0f;
        #pragma unroll
        for (int ks = 0; ks < 2; ++ks) {
            f16x8 vx, vh;
            #pragma unroll
            for (int i = 0; i < 8; ++i) {
                int k = ks * 32 + kg * 8 + i;   // same k-map for A & B -> cancels
                float xv = 0.0f, hv = 0.0f;
                if (jv)            xv = Wx[k * 200 + g * H_N + jl];
                if (jv && k < H_N) hv = Wh[k * 200 + g * H_N + jl];
                vx[i] = (_Float16)xv;
                vh[i] = (_Float16)hv;
            }
            wxf[g][ks] = vx;
            whf[g][ks] = vh;
        }
    }

    float c0 = 0.f, c1 = 0.f, c2 = 0.f, c3 = 0.f;  // fp32 cell state

    // zero h(0) in buffer 0
    for (int idx = tid; idx < 16 * 72; idx += 256)
        ((_Float16*)hb[0])[idx] = (_Float16)0.0f;

    // stage x(0) into buffer 0: thread -> (row tid>>4, 4 floats), coalesced
    const int xr  = tid >> 4;
    const int xf0 = (tid & 15) * 4;
    const float* xrow = x + (size_t)(R0 + xr) * ROWSTRIDE + xf0;
    {
        f32x4 xv = *reinterpret_cast<const f32x4*>(xrow);
        f16x4 xc;
        #pragma unroll
        for (int j = 0; j < 4; ++j) xc[j] = (_Float16)xv[j];
        *reinterpret_cast<f16x4*>(&xb[0][xr][xf0]) = xc;
    }
    __syncthreads();

    // One step: read frags from buf RB, prefetch next x, MFMA+gates,
    // write h/x to buf WB, ONE barrier. (Writes to WB cannot race: every
    // wave's reads of WB finished before the previous barrier.)
#define STEP(RB, WB, DO_PREF)                                                   \
    {                                                                           \
        f16x8 xa0 = *reinterpret_cast<const f16x8*>(&xb[RB][rowA][kg * 8]);     \
        f16x8 xa1 = *reinterpret_cast<const f16x8*>(&xb[RB][rowA][32 + kg * 8]);\
        f16x8 ha0 = *reinterpret_cast<const f16x8*>(&hb[RB][rowA][kg * 8]);     \
        f16x8 ha1 = *reinterpret_cast<const f16x8*>(&hb[RB][rowA][32 + kg * 8]);\
        f32x4 xp = {0.f, 0.f, 0.f, 0.f};                                        \
        if (DO_PREF) { xrow += F_N; xp = *reinterpret_cast<const f32x4*>(xrow); }\
        f32x4 ai = {bg[0], bg[0], bg[0], bg[0]};                                \
        f32x4 af = {bg[1], bg[1], bg[1], bg[1]};                                \
        f32x4 ag = {bg[2], bg[2], bg[2], bg[2]};                                \
        f32x4 ao = {bg[3], bg[3], bg[3], bg[3]};                                \
        ai = __builtin_amdgcn_mfma_f32_16x16x32_f16(xa0, wxf[0][0], ai, 0,0,0); \
        af = __builtin_amdgcn_mfma_f32_16x16x32_f16(xa0, wxf[1][0], af, 0,0,0); \
        ag = __builtin_amdgcn_mfma_f32_16x16x32_f16(xa0, wxf[2][0], ag, 0,0,0); \
        ao = __builtin_amdgcn_mfma_f32_16x16x32_f16(xa0, wxf[3][0], ao, 0,0,0); \
        ai = __builtin_amdgcn_mfma_f32_16x16x32_f16(xa1, wxf[0][1], ai, 0,0,0); \
        af = __builtin_amdgcn_mfma_f32_16x16x32_f16(xa1, wxf[1][1], af, 0,0,0); \
        ag = __builtin_amdgcn_mfma_f32_16x16x32_f16(xa1, wxf[2][1], ag, 0,0,0); \
        ao = __builtin_amdgcn_mfma_f32_16x16x32_f16(xa1, wxf[3][1], ao, 0,0,0); \
        ai = __builtin_amdgcn_mfma_f32_16x16x32_f16(ha0, whf[0][0], ai, 0,0,0); \
        af = __builtin_amdgcn_mfma_f32_16x16x32_f16(ha0, whf[1][0], af, 0,0,0); \
        ag = __builtin_amdgcn_mfma_f32_16x16x32_f16(ha0, whf[2][0], ag, 0,0,0); \
        ao = __builtin_amdgcn_mfma_f32_16x16x32_f16(ha0, whf[3][0], ao, 0,0,0); \
        ai = __builtin_amdgcn_mfma_f32_16x16x32_f16(ha1, whf[0][1], ai, 0,0,0); \
        af = __builtin_amdgcn_mfma_f32_16x16x32_f16(ha1, whf[1][1], af, 0,0,0); \
        ag = __builtin_amdgcn_mfma_f32_16x16x32_f16(ha1, whf[2][1], ag, 0,0,0); \
        ao = __builtin_amdgcn_mfma_f32_16x16x32_f16(ha1, whf[3][1], ao, 0,0,0); \
        {                                                                       \
            float cn;                                                           \
            cn = sigm_f(af[0]) * c0 + sigm_f(ai[0]) * tanh_f(ag[0]); c0 = cn;   \
            hb[WB][kg * 4 + 0][jl] = (_Float16)(sigm_f(ao[0]) * tanh_f(cn));    \
            cn = sigm_f(af[1]) * c1 + sigm_f(ai[1]) * tanh_f(ag[1]); c1 = cn;   \
            hb[WB][kg * 4 + 1][jl] = (_Float16)(sigm_f(ao[1]) * tanh_f(cn));    \
            cn = sigm_f(af[2]) * c2 + sigm_f(ai[2]) * tanh_f(ag[2]); c2 = cn;   \
            hb[WB][kg * 4 + 2][jl] = (_Float16)(sigm_f(ao[2]) * tanh_f(cn));    \
            cn = sigm_f(af[3]) * c3 + sigm_f(ai[3]) * tanh_f(ag[3]); c3 = cn;   \
            hb[WB][kg * 4 + 3][jl] = (_Float16)(sigm_f(ao[3]) * tanh_f(cn));    \
        }                                                                       \
        if (DO_PREF) {                                                          \
            f16x4 xc;                                                           \
            xc[0] = (_Float16)xp[0]; xc[1] = (_Float16)xp[1];                   \
            xc[2] = (_Float16)xp[2]; xc[3] = (_Float16)xp[3];                   \
            *reinterpret_cast<f16x4*>(&xb[WB][xr][xf0]) = xc;                   \
        }                                                                       \
        __syncthreads();                                                        \
    }

    // t = 0..165 (83 double-steps), then 166 (prefetch x167), then 167 (final)
    for (int it = 0; it < 83; ++it) {
        STEP(0, 1, true)
        STEP(1, 0, true)
    }
    STEP(0, 1, true)    // t = 166
    STEP(1, 0, false)   // t = 167, final h -> hb[0]
#undef STEP

    // ---- MLP head: relu(h@W1 + b1)@W2 + b2 + x[:, -1, 0] ------------------
    {
        const int r1 = tid & 15;
        const int u1 = tid >> 4;
        float hrow[H_N];
        #pragma unroll
        for (int k = 0; k < H_N; ++k) hrow[k] = (float)hb[0][r1][k];
        for (int uu = u1; uu < HEAD_N; uu += 16) {
            float s = b1[uu];
            #pragma unroll
            for (int k = 0; k < H_N; ++k) s += hrow[k] * W1[k * HEAD_N + uu];
            hrelu[r1][uu] = fmaxf(s, 0.0f);
        }
    }
    __syncthreads();
    {
        const int r2 = tid >> 4;
        const int p  = tid & 15;
        float s = 0.0f;
        for (int uu = p; uu < HEAD_N; uu += 16) s += hrelu[r2][uu] * W2[uu];
        #pragma unroll
        for (int off = 8; off > 0; off >>= 1) s += __shfl_xor(s, off, 16);
        if (p == 0) {
            float res = x[(size_t)(R0 + r2) * ROWSTRIDE + (T_N - 1) * F_N + 0];
            out[R0 + r2] = s + b2[0] + res;
        }
    }
}

extern "C" void kernel_launch(void* const* d_in, const int* in_sizes, int n_in,
                              void* d_out, int out_size, void* d_ws, size_t ws_size,
                              hipStream_t stream) {
    const float* x  = (const float*)d_in[0];
    const float* Wx = (const float*)d_in[1];
    const float* Wh = (const float*)d_in[2];
    const float* b  = (const float*)d_in[3];
    const float* W1 = (const float*)d_in[4];
    const float* b1 = (const float*)d_in[5];
    const float* W2 = (const float*)d_in[6];
    const float* b2 = (const float*)d_in[7];
    float* out = (float*)d_out;

    lstm_fused<<<dim3(B_N / 16), dim3(256), 0, stream>>>(x, Wx, Wh, b, W1, b1, W2, b2, out);
}

// Round 4
// 164.803 us; speedup vs baseline: 1.1767x; 1.1165x over previous
//
#include <hip/hip_runtime.h>

// LSTM (B=8192, T=168, F=64, H=50) + MLP head, fused, f16 MFMA + fp32 state.
// Round 4: round-3 structure (x@Wx precomputed one step ahead, 2-step-deep
// x prefetch, exp2-prescaled weights, 1 barrier/step) with the inline-asm
// v_exp_f32 replaced by the hazard-aware compiler builtin (round 3's failure:
// INLINEASM is not recognized as a TRANS producer, so the exp->consumer
// wait-state was not inserted).

#define B_N 8192
#define T_N 168
#define F_N 64
#define H_N 50
#define HEAD_N 100
#define ROWSTRIDE (T_N * F_N)  // 10752

typedef _Float16 f16x8 __attribute__((ext_vector_type(8)));
typedef _Float16 f16x4 __attribute__((ext_vector_type(4)));
typedef float    f32x4 __attribute__((ext_vector_type(4)));

#define LOG2E  1.4426950408889634f
#define LOG2E2 2.8853900817779268f

#define MFMA __builtin_amdgcn_mfma_f32_16x16x32_f16

__device__ __forceinline__ float rcp_f(float v) { return __builtin_amdgcn_rcpf(v); }
#if __has_builtin(__builtin_amdgcn_exp2f)
__device__ __forceinline__ float exp2_f(float v) { return __builtin_amdgcn_exp2f(v); }
#else
__device__ __forceinline__ float exp2_f(float v) { return __expf(0.6931471805599453f * v); }
#endif

__launch_bounds__(256, 2)
__global__ void lstm_fused(const float* __restrict__ x,
                           const float* __restrict__ Wx,
                           const float* __restrict__ Wh,
                           const float* __restrict__ b,
                           const float* __restrict__ W1,
                           const float* __restrict__ b1,
                           const float* __restrict__ W2,
                           const float* __restrict__ b2,
                           float* __restrict__ out)
{
    // stride 72 f16 (144 B): rows 16B-aligned, worst 2-way bank alias (free)
    __shared__ alignas(16) _Float16 xb[2][16][72];  // xb[t&1] holds x(t)
    __shared__ alignas(16) _Float16 hb[2][16][72];  // hb[t&1] holds h(t)
    __shared__ float hrelu[16][HEAD_N];

    const int tid  = threadIdx.x;
    const int lane = tid & 63;
    const int w    = tid >> 6;        // wave id = unit-tile (16 units each)
    const int rowA = lane & 15;       // A-frag row == C-frag col
    const int kg   = lane >> 4;       // k-group 0..3
    const int R0   = blockIdx.x * 16; // batch rows of this block

    // ---- weight B-fragments (VGPR-resident), prescaled to exp2 domain -----
    // col256 = g*64 + j ; this wave: j in [16w, 16w+16)
    f16x8 wxf[4][2], whf[4][2];
    float bg[4];
    const int  jl = w * 16 + rowA;    // unit index 0..63 (lane's column)
    const bool jv = (jl < H_N);
    #pragma unroll
    for (int g = 0; g < 4; ++g) {
        const float sc = (g == 2) ? LOG2E2 : LOG2E;   // g-gate: fold tanh's 2x
        bg[g] = jv ? b[g * H_N + jl] * sc : 0.0f;
        #pragma unroll
        for (int ks = 0; ks < 2; ++ks) {
            f16x8 vx, vh;
            #pragma unroll
            for (int i = 0; i < 8; ++i) {
                int k = ks * 32 + kg * 8 + i;   // same k-map for A & B -> cancels
                float xv = 0.0f, hv = 0.0f;
                if (jv)            xv = Wx[k * 200 + g * H_N + jl] * sc;
                if (jv && k < H_N) hv = Wh[k * 200 + g * H_N + jl] * sc;
                vx[i] = (_Float16)xv;
                vh[i] = (_Float16)hv;
            }
            wxf[g][ks] = vx;
            whf[g][ks] = vh;
        }
    }

    float c0 = 0.f, c1 = 0.f, c2 = 0.f, c3 = 0.f;  // fp32 cell state

    // zero h(0)
    for (int idx = tid; idx < 16 * 72; idx += 256)
        ((_Float16*)hb[0])[idx] = (_Float16)0.0f;

    // x staging map: thread -> (row tid>>4, 4 floats), coalesced 256B/row
    const int xr  = tid >> 4;
    const int xf0 = (tid & 15) * 4;
    const float* xrow = x + (size_t)(R0 + xr) * ROWSTRIDE + xf0;

    f32x4 xpr0, xpr1;   // in-flight x rows: xpr[t&1] written to LDS at step t
    {
        f32x4 v0 = *reinterpret_cast<const f32x4*>(xrow);
        f32x4 v1 = *reinterpret_cast<const f32x4*>(xrow + F_N);
        xpr0 = *reinterpret_cast<const f32x4*>(xrow + 2 * F_N);   // x(2)
        xpr1 = *reinterpret_cast<const f32x4*>(xrow + 3 * F_N);   // x(3)
        f16x4 a, c4;
        #pragma unroll
        for (int j = 0; j < 4; ++j) { a[j] = (_Float16)v0[j]; c4[j] = (_Float16)v1[j]; }
        *reinterpret_cast<f16x4*>(&xb[0][xr][xf0]) = a;   // x(0)
        *reinterpret_cast<f16x4*>(&xb[1][xr][xf0]) = c4;  // x(1)
    }
    const float* xld = xrow + 4 * F_N;   // next global load: x(4)
    __syncthreads();

    // ax = b + x(0) @ Wx  (precompute for step 0)
    f32x4 axi, axf, axg, axo;
    {
        f16x8 xa0 = *reinterpret_cast<const f16x8*>(&xb[0][rowA][kg * 8]);
        f16x8 xa1 = *reinterpret_cast<const f16x8*>(&xb[0][rowA][32 + kg * 8]);
        axi = (f32x4){bg[0], bg[0], bg[0], bg[0]};
        axf = (f32x4){bg[1], bg[1], bg[1], bg[1]};
        axg = (f32x4){bg[2], bg[2], bg[2], bg[2]};
        axo = (f32x4){bg[3], bg[3], bg[3], bg[3]};
        axi = MFMA(xa0, wxf[0][0], axi, 0, 0, 0);
        axf = MFMA(xa0, wxf[1][0], axf, 0, 0, 0);
        axg = MFMA(xa0, wxf[2][0], axg, 0, 0, 0);
        axo = MFMA(xa0, wxf[3][0], axo, 0, 0, 0);
        axi = MFMA(xa1, wxf[0][1], axi, 0, 0, 0);
        axf = MFMA(xa1, wxf[1][1], axf, 0, 0, 0);
        axg = MFMA(xa1, wxf[2][1], axg, 0, 0, 0);
        axo = MFMA(xa1, wxf[3][1], axo, 0, 0, 0);
    }
    __syncthreads();   // step 0 overwrites xb[0]; protect the reads above

    // gate: all-exp2-domain; writes h(t+1) f16 into hb[PW]
#define GATE1(PW, ii, cvar)                                                    \
    {                                                                          \
        float si_ = rcp_f(1.0f + exp2_f(-zi[ii]));                             \
        float sf_ = rcp_f(1.0f + exp2_f(-zf[ii]));                             \
        float tg_ = fmaf(-2.0f, rcp_f(1.0f + exp2_f(zg[ii])), 1.0f);           \
        float so_ = rcp_f(1.0f + exp2_f(-zo[ii]));                             \
        float cn_ = fmaf(sf_, cvar, si_ * tg_);                                \
        cvar = cn_;                                                            \
        float tc_ = fmaf(-2.0f, rcp_f(1.0f + exp2_f(LOG2E2 * cn_)), 1.0f);     \
        hb[PW][kg * 4 + ii][jl] = (_Float16)(so_ * tc_);                       \
    }

    // One step t (P = t&1): z = ax + h(t)@Wh ; ax' = b + x(t+1)@Wx (off-path);
    // LDS-write x(t+2) from reg; issue load x(t+4); gates; write h(t+1); barrier.
#define STEP(P, DO_XF, DO_XW, DO_LOAD)                                         \
    {                                                                          \
        f16x8 ha0 = *reinterpret_cast<const f16x8*>(&hb[P][rowA][kg * 8]);     \
        f16x8 ha1 = *reinterpret_cast<const f16x8*>(&hb[P][rowA][32 + kg * 8]);\
        f32x4 zi = MFMA(ha0, whf[0][0], axi, 0, 0, 0);                         \
        f32x4 zf = MFMA(ha0, whf[1][0], axf, 0, 0, 0);                         \
        f32x4 zg = MFMA(ha0, whf[2][0], axg, 0, 0, 0);                         \
        f32x4 zo = MFMA(ha0, whf[3][0], axo, 0, 0, 0);                         \
        zi = MFMA(ha1, whf[0][1], zi, 0, 0, 0);                                \
        zf = MFMA(ha1, whf[1][1], zf, 0, 0, 0);                                \
        zg = MFMA(ha1, whf[2][1], zg, 0, 0, 0);                                \
        zo = MFMA(ha1, whf[3][1], zo, 0, 0, 0);                                \
        if (DO_XF) {  /* ax for step t+1 from x(t+1) in xb[P^1] */             \
            f16x8 xa0 = *reinterpret_cast<const f16x8*>(&xb[P ^ 1][rowA][kg * 8]);      \
            f16x8 xa1 = *reinterpret_cast<const f16x8*>(&xb[P ^ 1][rowA][32 + kg * 8]); \
            axi = (f32x4){bg[0], bg[0], bg[0], bg[0]};                         \
            axf = (f32x4){bg[1], bg[1], bg[1], bg[1]};                         \
            axg = (f32x4){bg[2], bg[2], bg[2], bg[2]};                         \
            axo = (f32x4){bg[3], bg[3], bg[3], bg[3]};                         \
            axi = MFMA(xa0, wxf[0][0], axi, 0, 0, 0);                          \
            axf = MFMA(xa0, wxf[1][0], axf, 0, 0, 0);                          \
            axg = MFMA(xa0, wxf[2][0], axg, 0, 0, 0);                          \
            axo = MFMA(xa0, wxf[3][0], axo, 0, 0, 0);                          \
            axi = MFMA(xa1, wxf[0][1], axi, 0, 0, 0);                          \
            axf = MFMA(xa1, wxf[1][1], axf, 0, 0, 0);                          \
            axg = MFMA(xa1, wxf[2][1], axg, 0, 0, 0);                          \
            axo = MFMA(xa1, wxf[3][1], axo, 0, 0, 0);                          \
        }                                                                      \
        if (DO_XW) {  /* x(t+2) -> xb[P]; its frags were read at step t-1 */   \
            f16x4 xc;                                                          \
            xc[0] = (_Float16)xpr##P[0]; xc[1] = (_Float16)xpr##P[1];          \
            xc[2] = (_Float16)xpr##P[2]; xc[3] = (_Float16)xpr##P[3];          \
            *reinterpret_cast<f16x4*>(&xb[P][xr][xf0]) = xc;                   \
        }                                                                      \
        if (DO_LOAD) { xpr##P = *reinterpret_cast<const f32x4*>(xld); xld += F_N; } \
        GATE1(P ^ 1, 0, c0)                                                    \
        GATE1(P ^ 1, 1, c1)                                                    \
        GATE1(P ^ 1, 2, c2)                                                    \
        GATE1(P ^ 1, 3, c3)                                                    \
        __syncthreads();                                                       \
    }

    // t = 0..163 main, then peel 164..167 (drop loads/writes/frags at the edge)
    for (int it = 0; it < 82; ++it) {
        STEP(0, 1, 1, 1)
        STEP(1, 1, 1, 1)
    }
    STEP(0, 1, 1, 0)   // t=164: writes x(166)
    STEP(1, 1, 1, 0)   // t=165: writes x(167)
    STEP(0, 1, 0, 0)   // t=166: last ax precompute (x(167))
    STEP(1, 0, 0, 0)   // t=167: final -> h(168) in hb[0]
#undef STEP
#undef GATE1

    // ---- MLP head: relu(h@W1 + b1)@W2 + b2 + x[:, -1, 0] ------------------
    {
        const int r1 = tid & 15;
        const int u1 = tid >> 4;
        float hrow[H_N];
        #pragma unroll
        for (int k = 0; k < H_N; ++k) hrow[k] = (float)hb[0][r1][k];
        for (int uu = u1; uu < HEAD_N; uu += 16) {
            float s = b1[uu];
            #pragma unroll
            for (int k = 0; k < H_N; ++k) s += hrow[k] * W1[k * HEAD_N + uu];
            hrelu[r1][uu] = fmaxf(s, 0.0f);
        }
    }
    __syncthreads();
    {
        const int r2 = tid >> 4;
        const int p  = tid & 15;
        float s = 0.0f;
        for (int uu = p; uu < HEAD_N; uu += 16) s += hrelu[r2][uu] * W2[uu];
        #pragma unroll
        for (int off = 8; off > 0; off >>= 1) s += __shfl_xor(s, off, 16);
        if (p == 0) {
            float res = x[(size_t)(R0 + r2) * ROWSTRIDE + (T_N - 1) * F_N + 0];
            out[R0 + r2] = s + b2[0] + res;
        }
    }
}

extern "C" void kernel_launch(void* const* d_in, const int* in_sizes, int n_in,
                              void* d_out, int out_size, void* d_ws, size_t ws_size,
                              hipStream_t stream) {
    const float* x  = (const float*)d_in[0];
    const float* Wx = (const float*)d_in[1];
    const float* Wh = (const float*)d_in[2];
    const float* b  = (const float*)d_in[3];
    const float* W1 = (const float*)d_in[4];
    const float* b1 = (const float*)d_in[5];
    const float* W2 = (const float*)d_in[6];
    const float* b2 = (const float*)d_in[7];
    float* out = (float*)d_out;

    lstm_fused<<<dim3(B_N / 16), dim3(256), 0, stream>>>(x, Wx, Wh, b, W1, b1, W2, b2, out);
}